// Round 4
// baseline (2352.829 us; speedup 1.0000x reference)
//
#include <hip/hip_runtime.h>
#include <hip/hip_bf16.h>

// ---------------------------------------------------------------------------
// PAWSA — correctness anchor (round 4): VALU kernel, f32 OUTPUT.
// Inputs f32, output f32 (out0 [8192,49,96], out1 [8,3,96] at elem 38,535,168).
// bf16 used only for LDS capacity (x, W, k, v, O); all stores f32.
// One block per window; 8192 blocks x 256 threads; LDS 64,544 B.
// ---------------------------------------------------------------------------

typedef float f32x4 __attribute__((ext_vector_type(4)));
typedef short s16x4 __attribute__((ext_vector_type(4)));
using bf16 = __hip_bfloat16;

#define SCALE 0.17677669529663687f   // 32^-0.5

static __device__ inline float s2f(short s) {
    unsigned int u = ((unsigned int)(unsigned short)s) << 16;
    float f;
    __builtin_memcpy(&f, &u, 4);
    return f;
}
static __device__ inline short f2s(float f) {
    bf16 h = __float2bfloat16(f);
    short s;
    __builtin_memcpy(&s, &h, 2);
    return s;
}

// LDS byte offsets (all 8B-aligned)
#define OFF_XB 0        // short [52][96] x_ext            9984 B
#define OFF_WB 9984     // short [96][96] weight slice    18432 B
#define OFF_VB 28416    // short [52][32] v_h              3328 B
#define OFF_KB 31744    // short [52][32] k_h              3328 B
#define OFF_OB 35072    // short [49][96] O (concat heads) 9408 B
#define OFF_QH 44480    // float [49][32] q_h (pre-scaled) 6272 B
#define OFF_S  50752    // float [49][52] logits/probs    10192 B
#define OFF_SB 60944    // float [288] qkv_b               1152 B
#define OFF_PB 62096    // float [96]  proj_b               384 B
#define OFF_BT 62480    // float [516] bias_table          2064 B
#define LDS_BYTES 64544

__global__ __launch_bounds__(256, 2)
void pawsa_valu(const float* __restrict__ x, const float* __restrict__ mask,
                const float* __restrict__ uk, const float* __restrict__ fg,
                const float* __restrict__ bg,
                const float* __restrict__ qkv_w, const float* __restrict__ qkv_b,
                const float* __restrict__ proj_w, const float* __restrict__ proj_b,
                const float* __restrict__ bias_table, float* __restrict__ out)
{
    __shared__ char smem[LDS_BYTES];
    short* xb = (short*)(smem + OFF_XB);
    short* wb = (short*)(smem + OFF_WB);
    short* vb = (short*)(smem + OFF_VB);
    short* kb = (short*)(smem + OFF_KB);
    short* Ob = (short*)(smem + OFF_OB);
    float* qh = (float*)(smem + OFF_QH);
    float* S  = (float*)(smem + OFF_S);
    float* sb = (float*)(smem + OFF_SB);
    float* pb = (float*)(smem + OFF_PB);
    float* bt = (float*)(smem + OFF_BT);

    const int tid = threadIdx.x;
    const int w = blockIdx.x;        // window id = b*1024 + wi
    const int b = w >> 10;
    const int wi = w & 1023;

    // ---- stage x_ext [52][96] (f32 -> bf16), biases, bias_table ----
    for (int i = tid; i < 4992; i += 256) {
        int n = i / 96, c = i % 96;
        float v;
        if (n < 49) {
            v = x[((size_t)w * 49 + n) * 96 + c];
        } else {
            const float* pr = (n == 49) ? uk : (n == 50) ? fg : bg;
            v = pr[b * 96 + c];
        }
        xb[n * 96 + c] = f2s(v);
    }
    for (int i = tid; i < 288; i += 256) sb[i] = qkv_b[i];
    if (tid < 96) pb[tid] = proj_b[tid];
    for (int i = tid; i < 516; i += 256) bt[i] = bias_table[i];
    __syncthreads();

    // ---- per-head pipeline ----
    for (int h = 0; h < 3; ++h) {
        // stage W slice: wb[s*32+d][c] = qkv_w[s*96 + h*32 + d][c]
        for (int i = tid; i < 9216; i += 256) {
            int r = i / 96, c = i % 96;       // r = s*32 + d
            int s = r >> 5, d = r & 31;
            wb[i] = f2s(qkv_w[(s * 96 + h * 32 + d) * 96 + c]);
        }
        __syncthreads();

        // qkv_h: q rows 0..48 (scaled, f32), k rows 0..51 (bf16), v rows 0..51 (bf16)
        for (int i = tid; i < 4896; i += 256) {
            int s, n, d;
            if (i < 1568)      { s = 0; n = i >> 5;            d = i & 31; }
            else if (i < 3232) { s = 1; n = (i - 1568) >> 5;   d = (i - 1568) & 31; }
            else               { s = 2; n = (i - 3232) >> 5;   d = (i - 3232) & 31; }
            float acc = sb[s * 96 + h * 32 + d];
            const short* xr = xb + n * 96;
            const short* wr = wb + (s * 32 + d) * 96;
            #pragma unroll 6
            for (int c = 0; c < 96; c += 4) {
                s16x4 xa = *(const s16x4*)(xr + c);
                s16x4 wa = *(const s16x4*)(wr + c);
                acc += s2f(xa[0]) * s2f(wa[0]) + s2f(xa[1]) * s2f(wa[1])
                     + s2f(xa[2]) * s2f(wa[2]) + s2f(xa[3]) * s2f(wa[3]);
            }
            if (s == 0)      qh[n * 32 + d] = acc * SCALE;
            else if (s == 1) kb[n * 32 + d] = f2s(acc);
            else             vb[n * 32 + d] = f2s(acc);
        }
        __syncthreads();

        // S[n][c] = q_n . k_c + bias_table[REL_IDX[n,c]][h] + mask[wi,n,c<49]
        for (int i = tid; i < 2548; i += 256) {
            int n = i / 52, c = i % 52;
            float acc;
            if (c < 49) {
                int idx = (n / 7 - c / 7 + 6) * 13 + (n % 7 - c % 7 + 6);
                acc = bt[idx * 3 + h] + mask[(size_t)wi * 2401 + n * 49 + c];
            } else {
                acc = bt[(169 + c - 49) * 3 + h];
            }
            const float* qr = qh + n * 32;
            const short* kr = kb + c * 32;
            #pragma unroll 8
            for (int d = 0; d < 32; d += 4) {
                s16x4 ka = *(const s16x4*)(kr + d);
                acc += qr[d]     * s2f(ka[0]) + qr[d + 1] * s2f(ka[1])
                     + qr[d + 2] * s2f(ka[2]) + qr[d + 3] * s2f(ka[3]);
            }
            S[i] = acc;
        }
        __syncthreads();

        // softmax per query row (52 cols)
        if (tid < 49) {
            float* Sr = S + tid * 52;
            float m = Sr[0];
            for (int c = 1; c < 52; ++c) m = fmaxf(m, Sr[c]);
            float sum = 0.f;
            for (int c = 0; c < 52; ++c) { float e = __expf(Sr[c] - m); Sr[c] = e; sum += e; }
            float inv = 1.0f / sum;
            for (int c = 0; c < 52; ++c) Sr[c] *= inv;
        }
        __syncthreads();

        // O_h = P @ V  -> Ob[n][h*32+d]
        for (int i = tid; i < 1568; i += 256) {
            int n = i >> 5, d = i & 31;
            float acc = 0.f;
            const float* Pr = S + n * 52;
            #pragma unroll 4
            for (int c = 0; c < 52; ++c)
                acc += Pr[c] * s2f(vb[c * 32 + d]);
            Ob[n * 96 + h * 32 + d] = f2s(acc);
        }
        __syncthreads();   // protects wb re-stage and S reuse next head
    }

    // ---- projection (f32 stores) ----
    for (int i = tid; i < 9216; i += 256) wb[i] = f2s(proj_w[i]);
    __syncthreads();
    for (int i = tid; i < 4704; i += 256) {
        int n = i / 96, o = i % 96;
        float acc = pb[o];
        const short* Or = Ob + n * 96;
        const short* wr = wb + o * 96;
        #pragma unroll 6
        for (int c = 0; c < 96; c += 4) {
            s16x4 oa = *(const s16x4*)(Or + c);
            s16x4 wa = *(const s16x4*)(wr + c);
            acc += s2f(oa[0]) * s2f(wa[0]) + s2f(oa[1]) * s2f(wa[1])
                 + s2f(oa[2]) * s2f(wa[2]) + s2f(oa[3]) * s2f(wa[3]);
        }
        out[((size_t)w * 49 + n) * 96 + o] = acc;
    }
}

// ---------------- prior highway: v_hw = proj(v(qkv(prior))) ----------------
__global__ __launch_bounds__(128)
void pawsa_prior(const float* __restrict__ uk, const float* __restrict__ fg,
                 const float* __restrict__ bg,
                 const float* __restrict__ qkv_w, const float* __restrict__ qkv_b,
                 const float* __restrict__ proj_w, const float* __restrict__ proj_b,
                 float* __restrict__ out_vhw)
{
    int blk = blockIdx.x;             // 24 = 8 batches * 3 priors
    int b = blk / 3, p = blk % 3;
    int t = threadIdx.x;
    __shared__ float prr[96], vf[96];
    const float* src = (p == 0) ? uk : (p == 1) ? fg : bg;
    if (t < 96) prr[t] = src[b * 96 + t];
    __syncthreads();
    if (t < 96) {
        float acc = qkv_b[192 + t];
        for (int k = 0; k < 96; ++k)
            acc += prr[k] * qkv_w[(192 + t) * 96 + k];
        vf[t] = acc;
    }
    __syncthreads();
    if (t < 96) {
        float acc = proj_b[t];
        for (int c = 0; c < 96; ++c)
            acc += vf[c] * proj_w[t * 96 + c];
        out_vhw[(b * 3 + p) * 96 + t] = acc;
    }
}

extern "C" void kernel_launch(void* const* d_in, const int* in_sizes, int n_in,
                              void* d_out, int out_size, void* d_ws, size_t ws_size,
                              hipStream_t stream) {
    const float* x          = (const float*)d_in[0];
    const float* mask       = (const float*)d_in[1];
    const float* uk         = (const float*)d_in[2];
    const float* fg         = (const float*)d_in[3];
    const float* bg         = (const float*)d_in[4];
    const float* qkv_w      = (const float*)d_in[5];
    const float* qkv_b      = (const float*)d_in[6];
    const float* proj_w     = (const float*)d_in[7];
    const float* proj_b     = (const float*)d_in[8];
    const float* bias_table = (const float*)d_in[9];
    float* out = (float*)d_out;

    pawsa_prior<<<24, 128, 0, stream>>>(uk, fg, bg, qkv_w, qkv_b, proj_w, proj_b,
                                        out + (size_t)8192 * 49 * 96);
    pawsa_valu<<<8192, 256, 0, stream>>>(x, mask, uk, fg, bg, qkv_w, qkv_b,
                                         proj_w, proj_b, bias_table, out);
}

// Round 5
// 453.369 us; speedup vs baseline: 5.1897x; 5.1897x over previous
//
#include <hip/hip_runtime.h>
#include <hip/hip_bf16.h>

// ---------------------------------------------------------------------------
// PAWSA fused windowed attention, MI355X / gfx950 — MFMA pipeline (round 5).
// Inputs f32, output f32 (out0 [8192,49,96], out1 v_hw [8,3,96] at elem
// offset 38,535,168). One block per window (8192 x 256 threads), bf16 MFMA
// 16x16x32 with fp32 accumulation; f32->bf16 conversion at stage/load time.
// LDS 64,776 B -> 2 blocks/CU.
// Structure validated: R2 MFMA output == verified VALU output (bit-identical
// absmax under the R2/R3 scrambled-read comparison).
// ---------------------------------------------------------------------------

typedef __bf16 bf16x8 __attribute__((ext_vector_type(8)));
typedef float  f32x4  __attribute__((ext_vector_type(4)));
typedef short  s16x4  __attribute__((ext_vector_type(4)));
using bf16 = __hip_bfloat16;

#define SCALE 0.17677669529663687f   // 32^-0.5

// LDS partition (units: 16-bit elements)
#define LDS_X     0       // [64][104] x_ext (bf16), reused as O (concat heads)
#define LDS_Q     6656    // [64][104] q (all heads: col = h*32+d)
#define LDS_K     13312   // [64][104] k
#define LDS_VT    19968   // [96][72]  v transposed: vt[h*32+d][token]
#define LDS_P     26880   // [64][72]  P (bf16 probs, per head)
#define LDS_BIAS  31488   // [516]     bias_table (bf16)
#define LDS_QKVB  32004   // [288]
#define LDS_PROJB 32292   // [96]
#define LDS_TOT   32388   // shorts -> 64,776 bytes

static __device__ inline float s2f(short s) {
    unsigned int u = ((unsigned int)(unsigned short)s) << 16;
    float f;
    __builtin_memcpy(&f, &u, 4);
    return f;
}
static __device__ inline short f2s(float f) {
    bf16 h = __float2bfloat16(f);
    short s;
    __builtin_memcpy(&s, &h, 2);
    return s;
}
// load 8 consecutive f32, convert to bf16x8 (MFMA operand fragment)
static __device__ inline bf16x8 ldw8(const float* p) {
    f32x4 a = *reinterpret_cast<const f32x4*>(p);
    f32x4 b = *reinterpret_cast<const f32x4*>(p + 4);
    bf16x8 r;
    #pragma unroll
    for (int i = 0; i < 4; ++i) {
        r[i]     = (__bf16)a[i];
        r[i + 4] = (__bf16)b[i];
    }
    return r;
}

__global__ __launch_bounds__(256, 2)
void pawsa_main(const float* __restrict__ x, const float* __restrict__ mask,
                const float* __restrict__ uk, const float* __restrict__ fg,
                const float* __restrict__ bg,
                const float* __restrict__ qkv_w, const float* __restrict__ qkv_b,
                const float* __restrict__ proj_w, const float* __restrict__ proj_b,
                const float* __restrict__ bias_table, float* __restrict__ out)
{
    __shared__ short smem[LDS_TOT];

    const int tid  = threadIdx.x;
    const int w    = blockIdx.x;       // window id
    const int b    = w >> 10;          // batch (nW = 1024)
    const int wi   = w & 1023;         // window-in-batch
    const int lane = tid & 63;
    const int wid  = tid >> 6;         // wave id 0..3
    const int lr   = lane & 15;        // row/col within 16-tile
    const int lg   = lane >> 4;        // k-group 0..3

    // ---------------- stage x_ext (f32 -> bf16) into LDS [64][104] ----------
    #pragma unroll
    for (int it = 0; it < 6; ++it) {
        int idx = tid + it * 256;          // 0..1535 == [64 rows][24 chunks of 4]
        int n = idx / 24, c4 = idx % 24;
        f32x4 v = (f32x4)0.f;
        if (n < 49) {
            v = *reinterpret_cast<const f32x4*>(x + ((size_t)w * 49 + n) * 96 + c4 * 4);
        } else if (n < 52) {
            const float* pr = (n == 49) ? uk : (n == 50) ? fg : bg;
            v = *reinterpret_cast<const f32x4*>(pr + b * 96 + c4 * 4);
        }
        s16x4 h;
        #pragma unroll
        for (int i = 0; i < 4; ++i) h[i] = f2s(v[i]);
        *reinterpret_cast<s16x4*>(&smem[LDS_X + n * 104 + c4 * 4]) = h;
    }
    for (int i = tid; i < 516; i += 256) smem[LDS_BIAS + i] = f2s(bias_table[i]);
    for (int i = tid; i < 288; i += 256) smem[LDS_QKVB + i] = f2s(qkv_b[i]);
    if (tid < 96) smem[LDS_PROJB + tid] = f2s(proj_b[tid]);
    __syncthreads();

    // ---------------- QKV GEMM: [64x96] @ W^T[96x288] ----------------
    // waves split the 18 N-tiles {5,5,4,4} so each W fragment is read once/block
    const int nt0   = wid * 5 - (wid == 3 ? 1 : 0);       // 0,5,10,14
    const int ntEnd = nt0 + (wid < 2 ? 5 : 4);

    {
        f32x4 acc[5][4];
        #pragma unroll
        for (int i = 0; i < 5; ++i)
            #pragma unroll
            for (int mt = 0; mt < 4; ++mt) acc[i][mt] = (f32x4)0.f;

        #pragma unroll
        for (int ks = 0; ks < 3; ++ks) {
            bf16x8 a[4];
            #pragma unroll
            for (int mt = 0; mt < 4; ++mt)
                a[mt] = *reinterpret_cast<const bf16x8*>(
                    &smem[LDS_X + (mt * 16 + lr) * 104 + ks * 32 + lg * 8]);
            #pragma unroll
            for (int i = 0; i < 5; ++i) {
                int nt = nt0 + i;
                if (nt < ntEnd) {
                    bf16x8 bw = ldw8(qkv_w + (nt * 16 + lr) * 96 + ks * 32 + lg * 8);
                    #pragma unroll
                    for (int mt = 0; mt < 4; ++mt)
                        acc[i][mt] = __builtin_amdgcn_mfma_f32_16x16x32_bf16(
                            a[mt], bw, acc[i][mt], 0, 0, 0);
                }
            }
        }
        // scatter D -> q/k/vt LDS (+ qkv bias)
        #pragma unroll
        for (int i = 0; i < 5; ++i) {
            int nt = nt0 + i;
            if (nt >= ntEnd) continue;
            int o = nt * 16 + lr;                 // output channel 0..287
            float bias = s2f(smem[LDS_QKVB + o]);
            int s   = nt / 6;                     // 0=q 1=k 2=v (o/96)
            int rem = o - s * 96;                 // channel within q/k/v
            #pragma unroll
            for (int mt = 0; mt < 4; ++mt) {
                #pragma unroll
                for (int j = 0; j < 4; ++j) {
                    int n = mt * 16 + lg * 4 + j;
                    short hv = f2s(acc[i][mt][j] + bias);
                    if (s == 0)      smem[LDS_Q  + n * 104 + rem] = hv;
                    else if (s == 1) smem[LDS_K  + n * 104 + rem] = hv;
                    else             smem[LDS_VT + rem * 72 + n]  = hv;
                }
            }
        }
    }
    __syncthreads();
    // After this barrier all remaining LDS traffic is wave-private rows.

    // hoist mask + relative-position index (head-independent)
    float mk[4][4];
    int   bidx[4][4];
    #pragma unroll
    for (int nt = 0; nt < 4; ++nt) {
        int c = nt * 16 + lr;                     // key col 0..63
        #pragma unroll
        for (int j = 0; j < 4; ++j) {
            int n = wid * 16 + lg * 4 + j;        // query row 0..63
            float m = 0.f;
            int idx = 171;
            if (c < 49) {
                idx = (n / 7 - c / 7 + 6) * 13 + ((n % 7) - (c % 7) + 6);
                if (idx > 171) idx = 171;         // garbage rows n>=49 (discarded)
                if (n < 49)
                    m = mask[(size_t)wi * 2401 + n * 49 + c];
            } else if (c < 52) {
                idx = 169 + (c - 49);
            }
            mk[nt][j] = m;
            bidx[nt][j] = idx;
        }
    }

    // ---------------- per-head attention ----------------
    #pragma unroll
    for (int h = 0; h < 3; ++h) {
        // S = q @ k^T   (wave owns query rows wid*16..wid*16+15)
        bf16x8 aq = *reinterpret_cast<const bf16x8*>(
            &smem[LDS_Q + (wid * 16 + lr) * 104 + h * 32 + lg * 8]);
        f32x4 sacc[4];
        #pragma unroll
        for (int nt = 0; nt < 4; ++nt) {
            bf16x8 bk = *reinterpret_cast<const bf16x8*>(
                &smem[LDS_K + (nt * 16 + lr) * 104 + h * 32 + lg * 8]);
            sacc[nt] = __builtin_amdgcn_mfma_f32_16x16x32_bf16(aq, bk, (f32x4)0.f, 0, 0, 0);
        }
        // logits
        float lgt[4][4];
        #pragma unroll
        for (int nt = 0; nt < 4; ++nt) {
            int c = nt * 16 + lr;
            #pragma unroll
            for (int j = 0; j < 4; ++j) {
                float v = -1e30f;
                if (c < 52)
                    v = sacc[nt][j] * SCALE
                        + s2f(smem[LDS_BIAS + bidx[nt][j] * 3 + h]) + mk[nt][j];
                lgt[nt][j] = v;
            }
        }
        // softmax over 52 cols: per-lane partial over nt, then 16-lane xor-reduce
        float pr[4][4];
        #pragma unroll
        for (int j = 0; j < 4; ++j) {
            float m = fmaxf(fmaxf(lgt[0][j], lgt[1][j]), fmaxf(lgt[2][j], lgt[3][j]));
            m = fmaxf(m, __shfl_xor(m, 1));
            m = fmaxf(m, __shfl_xor(m, 2));
            m = fmaxf(m, __shfl_xor(m, 4));
            m = fmaxf(m, __shfl_xor(m, 8));
            float sum = 0.f;
            #pragma unroll
            for (int nt = 0; nt < 4; ++nt) {
                pr[nt][j] = __expf(lgt[nt][j] - m);
                sum += pr[nt][j];
            }
            sum += __shfl_xor(sum, 1);
            sum += __shfl_xor(sum, 2);
            sum += __shfl_xor(sum, 4);
            sum += __shfl_xor(sum, 8);
            float inv = 1.0f / sum;
            #pragma unroll
            for (int nt = 0; nt < 4; ++nt) pr[nt][j] *= inv;
        }
        // write P (wave-private rows) to LDS as bf16
        #pragma unroll
        for (int nt = 0; nt < 4; ++nt)
            #pragma unroll
            for (int j = 0; j < 4; ++j)
                smem[LDS_P + (wid * 16 + lg * 4 + j) * 72 + nt * 16 + lr] = f2s(pr[nt][j]);

        // O_h = P @ V   (K = 52 padded to 64; P cols 52..63 are exact zeros)
        f32x4 ov[2] = {(f32x4)0.f, (f32x4)0.f};
        #pragma unroll
        for (int ks = 0; ks < 2; ++ks) {
            bf16x8 ap = *reinterpret_cast<const bf16x8*>(
                &smem[LDS_P + (wid * 16 + lr) * 72 + ks * 32 + lg * 8]);
            #pragma unroll
            for (int nt2 = 0; nt2 < 2; ++nt2) {
                bf16x8 bv = *reinterpret_cast<const bf16x8*>(
                    &smem[LDS_VT + (h * 32 + nt2 * 16 + lr) * 72 + ks * 32 + lg * 8]);
                ov[nt2] = __builtin_amdgcn_mfma_f32_16x16x32_bf16(ap, bv, ov[nt2], 0, 0, 0);
            }
        }
        // store O into LDS_X (reuse; wave-private rows)
        #pragma unroll
        for (int nt2 = 0; nt2 < 2; ++nt2)
            #pragma unroll
            for (int j = 0; j < 4; ++j)
                smem[LDS_X + (wid * 16 + lg * 4 + j) * 104 + h * 32 + nt2 * 16 + lr]
                    = f2s(ov[nt2][j]);
    }

    // ---------------- projection: [64x96] @ proj_w^T[96x96] ----------------
    f32x4 po[6];
    #pragma unroll
    for (int nt = 0; nt < 6; ++nt) po[nt] = (f32x4)0.f;
    #pragma unroll
    for (int ks = 0; ks < 3; ++ks) {
        bf16x8 a = *reinterpret_cast<const bf16x8*>(
            &smem[LDS_X + (wid * 16 + lr) * 104 + ks * 32 + lg * 8]);
        #pragma unroll
        for (int nt = 0; nt < 6; ++nt) {
            bf16x8 bp = ldw8(proj_w + (nt * 16 + lr) * 96 + ks * 32 + lg * 8);
            po[nt] = __builtin_amdgcn_mfma_f32_16x16x32_bf16(a, bp, po[nt], 0, 0, 0);
        }
    }
    #pragma unroll
    for (int nt = 0; nt < 6; ++nt) {
        int col = nt * 16 + lr;
        float pb = s2f(smem[LDS_PROJB + col]);
        #pragma unroll
        for (int j = 0; j < 4; ++j) {
            int n = wid * 16 + lg * 4 + j;
            if (n < 49)
                out[((size_t)w * 49 + n) * 96 + col] = po[nt][j] + pb;
        }
    }
}

// ---------------- prior highway: v_hw = proj(v(qkv(prior))) ----------------
__global__ __launch_bounds__(128)
void pawsa_prior(const float* __restrict__ uk, const float* __restrict__ fg,
                 const float* __restrict__ bg,
                 const float* __restrict__ qkv_w, const float* __restrict__ qkv_b,
                 const float* __restrict__ proj_w, const float* __restrict__ proj_b,
                 float* __restrict__ out_vhw)
{
    int blk = blockIdx.x;             // 24 = 8 batches * 3 priors
    int b = blk / 3, p = blk % 3;
    int t = threadIdx.x;
    __shared__ float prr[96], vf[96];
    const float* src = (p == 0) ? uk : (p == 1) ? fg : bg;
    if (t < 96) prr[t] = src[b * 96 + t];
    __syncthreads();
    if (t < 96) {
        float acc = qkv_b[192 + t];
        for (int k = 0; k < 96; ++k)
            acc += prr[k] * qkv_w[(192 + t) * 96 + k];
        vf[t] = acc;
    }
    __syncthreads();
    if (t < 96) {
        float acc = proj_b[t];
        for (int c = 0; c < 96; ++c)
            acc += vf[c] * proj_w[t * 96 + c];
        out_vhw[(b * 3 + p) * 96 + t] = acc;
    }
}

extern "C" void kernel_launch(void* const* d_in, const int* in_sizes, int n_in,
                              void* d_out, int out_size, void* d_ws, size_t ws_size,
                              hipStream_t stream) {
    const float* x          = (const float*)d_in[0];
    const float* mask       = (const float*)d_in[1];
    const float* uk         = (const float*)d_in[2];
    const float* fg         = (const float*)d_in[3];
    const float* bg         = (const float*)d_in[4];
    const float* qkv_w      = (const float*)d_in[5];
    const float* qkv_b      = (const float*)d_in[6];
    const float* proj_w     = (const float*)d_in[7];
    const float* proj_b     = (const float*)d_in[8];
    const float* bias_table = (const float*)d_in[9];
    float* out = (float*)d_out;

    pawsa_prior<<<24, 128, 0, stream>>>(uk, fg, bg, qkv_w, qkv_b, proj_w, proj_b,
                                        out + (size_t)8192 * 49 * 96);
    pawsa_main<<<8192, 256, 0, stream>>>(x, mask, uk, fg, bg, qkv_w, qkv_b,
                                         proj_w, proj_b, bias_table, out);
}

// Round 6
// 445.384 us; speedup vs baseline: 5.2827x; 1.0179x over previous
//
#include <hip/hip_runtime.h>
#include <hip/hip_bf16.h>

// ---------------------------------------------------------------------------
// PAWSA fused windowed attention, MI355X / gfx950 — round 6: LDS diet.
// Inputs f32, output f32 (out0 [8192,49,96], out1 v_hw [8,3,96] at elem
// offset 38,535,168). One block per window (8192 x 256 threads), bf16 MFMA
// 16x16x32, fp32 accumulation.
// LDS 47,240 B -> 3 blocks/CU (was 64,776 B -> 2 blocks/CU).
//   - Q aliases the X buffer (rows<52 overwritten after an extra barrier;
//     rows 52..63 remain staged zeros). O also aliases it (row-private).
//   - K shrunk to [52][104], scatter predicated n<52; B-frag over-reads land
//     in VT (finite, always written) and only feed masked logit cols >=52.
//   - P shrunk to [52][72], writes predicated; over-reads land in the bias
//     table (finite) and only feed discarded output rows >=52.
// ---------------------------------------------------------------------------

typedef __bf16 bf16x8 __attribute__((ext_vector_type(8)));
typedef float  f32x4  __attribute__((ext_vector_type(4)));
typedef short  s16x4  __attribute__((ext_vector_type(4)));
using bf16 = __hip_bfloat16;

#define SCALE 0.17677669529663687f   // 32^-0.5

// LDS partition (units: 16-bit elements)
#define LDS_XQ    0       // [64][104] x_ext -> then q (rows<52) -> then O
#define LDS_K     6656    // [52][104] k (tokens x channels)
#define LDS_VT    12064   // [96][72]  v transposed: vt[h*32+d][token]
#define LDS_P     18976   // [52][72]  P (bf16 probs, per head)
#define LDS_BIAS  22720   // [516]     bias_table (bf16)
#define LDS_QKVB  23236   // [288]
#define LDS_PROJB 23524   // [96]
#define LDS_TOT   23620   // shorts -> 47,240 bytes

static __device__ inline float s2f(short s) {
    unsigned int u = ((unsigned int)(unsigned short)s) << 16;
    float f;
    __builtin_memcpy(&f, &u, 4);
    return f;
}
static __device__ inline short f2s(float f) {
    bf16 h = __float2bfloat16(f);
    short s;
    __builtin_memcpy(&s, &h, 2);
    return s;
}
// load 8 consecutive f32, convert to bf16x8 (MFMA operand fragment)
static __device__ inline bf16x8 ldw8(const float* p) {
    f32x4 a = *reinterpret_cast<const f32x4*>(p);
    f32x4 b = *reinterpret_cast<const f32x4*>(p + 4);
    bf16x8 r;
    #pragma unroll
    for (int i = 0; i < 4; ++i) {
        r[i]     = (__bf16)a[i];
        r[i + 4] = (__bf16)b[i];
    }
    return r;
}

__global__ __launch_bounds__(256, 4)
void pawsa_main(const float* __restrict__ x, const float* __restrict__ mask,
                const float* __restrict__ uk, const float* __restrict__ fg,
                const float* __restrict__ bg,
                const float* __restrict__ qkv_w, const float* __restrict__ qkv_b,
                const float* __restrict__ proj_w, const float* __restrict__ proj_b,
                const float* __restrict__ bias_table, float* __restrict__ out)
{
    __shared__ short smem[LDS_TOT];

    const int tid  = threadIdx.x;
    const int w    = blockIdx.x;       // window id
    const int b    = w >> 10;          // batch (nW = 1024)
    const int wi   = w & 1023;         // window-in-batch
    const int lane = tid & 63;
    const int wid  = tid >> 6;         // wave id 0..3
    const int lr   = lane & 15;        // row/col within 16-tile
    const int lg   = lane >> 4;        // k-group 0..3

    // ---------------- stage x_ext (f32 -> bf16) into LDS_XQ [64][104] -------
    #pragma unroll
    for (int it = 0; it < 6; ++it) {
        int idx = tid + it * 256;          // 0..1535 == [64 rows][24 chunks of 4]
        int n = idx / 24, c4 = idx % 24;
        f32x4 v = (f32x4)0.f;
        if (n < 49) {
            v = *reinterpret_cast<const f32x4*>(x + ((size_t)w * 49 + n) * 96 + c4 * 4);
        } else if (n < 52) {
            const float* pr = (n == 49) ? uk : (n == 50) ? fg : bg;
            v = *reinterpret_cast<const f32x4*>(pr + b * 96 + c4 * 4);
        }
        s16x4 h;
        #pragma unroll
        for (int i = 0; i < 4; ++i) h[i] = f2s(v[i]);
        *reinterpret_cast<s16x4*>(&smem[LDS_XQ + n * 104 + c4 * 4]) = h;
    }
    for (int i = tid; i < 516; i += 256) smem[LDS_BIAS + i] = f2s(bias_table[i]);
    for (int i = tid; i < 288; i += 256) smem[LDS_QKVB + i] = f2s(qkv_b[i]);
    if (tid < 96) smem[LDS_PROJB + tid] = f2s(proj_b[tid]);
    __syncthreads();

    // ---------------- QKV GEMM: [64x96] @ W^T[96x288] ----------------
    // waves split the 18 N-tiles {5,5,4,4} so each W fragment is read once/block
    const int nt0   = wid * 5 - (wid == 3 ? 1 : 0);       // 0,5,10,14
    const int ntEnd = nt0 + (wid < 2 ? 5 : 4);

    f32x4 acc[5][4];
    #pragma unroll
    for (int i = 0; i < 5; ++i)
        #pragma unroll
        for (int mt = 0; mt < 4; ++mt) acc[i][mt] = (f32x4)0.f;

    #pragma unroll
    for (int ks = 0; ks < 3; ++ks) {
        bf16x8 a[4];
        #pragma unroll
        for (int mt = 0; mt < 4; ++mt)
            a[mt] = *reinterpret_cast<const bf16x8*>(
                &smem[LDS_XQ + (mt * 16 + lr) * 104 + ks * 32 + lg * 8]);
        #pragma unroll
        for (int i = 0; i < 5; ++i) {
            int nt = nt0 + i;
            if (nt < ntEnd) {
                bf16x8 bw = ldw8(qkv_w + (nt * 16 + lr) * 96 + ks * 32 + lg * 8);
                #pragma unroll
                for (int mt = 0; mt < 4; ++mt)
                    acc[i][mt] = __builtin_amdgcn_mfma_f32_16x16x32_bf16(
                        a[mt], bw, acc[i][mt], 0, 0, 0);
            }
        }
    }
    __syncthreads();   // all X reads complete before q overwrites XQ rows<52

    // scatter D -> q (into XQ, rows<52) / k (rows<52) / vt (+ qkv bias)
    #pragma unroll
    for (int i = 0; i < 5; ++i) {
        int nt = nt0 + i;
        if (nt >= ntEnd) continue;
        int o = nt * 16 + lr;                 // output channel 0..287
        float bias = s2f(smem[LDS_QKVB + o]);
        int s   = nt / 6;                     // 0=q 1=k 2=v (o/96)
        int rem = o - s * 96;                 // channel within q/k/v
        #pragma unroll
        for (int mt = 0; mt < 4; ++mt) {
            #pragma unroll
            for (int j = 0; j < 4; ++j) {
                int n = mt * 16 + lg * 4 + j;
                short hv = f2s(acc[i][mt][j] + bias);
                if (s == 0)      { if (n < 52) smem[LDS_XQ + n * 104 + rem] = hv; }
                else if (s == 1) { if (n < 52) smem[LDS_K  + n * 104 + rem] = hv; }
                else             smem[LDS_VT + rem * 72 + n]  = hv;
            }
        }
    }
    __syncthreads();
    // After this barrier all remaining LDS traffic is wave-private rows
    // (K, VT read-only; XQ/P rows owned per-wave).

    // hoist mask + relative-position index (head-independent)
    float mk[4][4];
    int   bidx[4][4];
    #pragma unroll
    for (int nt = 0; nt < 4; ++nt) {
        int c = nt * 16 + lr;                     // key col 0..63
        #pragma unroll
        for (int j = 0; j < 4; ++j) {
            int n = wid * 16 + lg * 4 + j;        // query row 0..63
            float m = 0.f;
            int idx = 171;
            if (c < 49) {
                idx = (n / 7 - c / 7 + 6) * 13 + ((n % 7) - (c % 7) + 6);
                if (idx > 171) idx = 171;         // garbage rows n>=49 (discarded)
                if (n < 49)
                    m = mask[(size_t)wi * 2401 + n * 49 + c];
            } else if (c < 52) {
                idx = 169 + (c - 49);
            }
            mk[nt][j] = m;
            bidx[nt][j] = idx;
        }
    }

    // ---------------- per-head attention ----------------
    #pragma unroll
    for (int h = 0; h < 3; ++h) {
        // S = q @ k^T   (wave owns query rows wid*16..wid*16+15)
        bf16x8 aq = *reinterpret_cast<const bf16x8*>(
            &smem[LDS_XQ + (wid * 16 + lr) * 104 + h * 32 + lg * 8]);
        f32x4 sacc[4];
        #pragma unroll
        for (int nt = 0; nt < 4; ++nt) {
            bf16x8 bk = *reinterpret_cast<const bf16x8*>(
                &smem[LDS_K + (nt * 16 + lr) * 104 + h * 32 + lg * 8]);
            sacc[nt] = __builtin_amdgcn_mfma_f32_16x16x32_bf16(aq, bk, (f32x4)0.f, 0, 0, 0);
        }
        // logits
        float lgt[4][4];
        #pragma unroll
        for (int nt = 0; nt < 4; ++nt) {
            int c = nt * 16 + lr;
            #pragma unroll
            for (int j = 0; j < 4; ++j) {
                float v = -1e30f;
                if (c < 52)
                    v = sacc[nt][j] * SCALE
                        + s2f(smem[LDS_BIAS + bidx[nt][j] * 3 + h]) + mk[nt][j];
                lgt[nt][j] = v;
            }
        }
        // softmax over 52 cols: per-lane partial over nt, then 16-lane xor-reduce
        float pr[4][4];
        #pragma unroll
        for (int j = 0; j < 4; ++j) {
            float m = fmaxf(fmaxf(lgt[0][j], lgt[1][j]), fmaxf(lgt[2][j], lgt[3][j]));
            m = fmaxf(m, __shfl_xor(m, 1));
            m = fmaxf(m, __shfl_xor(m, 2));
            m = fmaxf(m, __shfl_xor(m, 4));
            m = fmaxf(m, __shfl_xor(m, 8));
            float sum = 0.f;
            #pragma unroll
            for (int nt = 0; nt < 4; ++nt) {
                pr[nt][j] = __expf(lgt[nt][j] - m);
                sum += pr[nt][j];
            }
            sum += __shfl_xor(sum, 1);
            sum += __shfl_xor(sum, 2);
            sum += __shfl_xor(sum, 4);
            sum += __shfl_xor(sum, 8);
            float inv = 1.0f / sum;
            #pragma unroll
            for (int nt = 0; nt < 4; ++nt) pr[nt][j] *= inv;
        }
        // write P (wave-private rows, predicated <52) to LDS as bf16
        #pragma unroll
        for (int nt = 0; nt < 4; ++nt)
            #pragma unroll
            for (int j = 0; j < 4; ++j) {
                int prow = wid * 16 + lg * 4 + j;
                if (prow < 52)
                    smem[LDS_P + prow * 72 + nt * 16 + lr] = f2s(pr[nt][j]);
            }

        // O_h = P @ V   (K = 52 padded to 64; P cols 52..63 are exact zeros)
        f32x4 ov[2] = {(f32x4)0.f, (f32x4)0.f};
        #pragma unroll
        for (int ks = 0; ks < 2; ++ks) {
            bf16x8 ap = *reinterpret_cast<const bf16x8*>(
                &smem[LDS_P + (wid * 16 + lr) * 72 + ks * 32 + lg * 8]);
            #pragma unroll
            for (int nt2 = 0; nt2 < 2; ++nt2) {
                bf16x8 bv = *reinterpret_cast<const bf16x8*>(
                    &smem[LDS_VT + (h * 32 + nt2 * 16 + lr) * 72 + ks * 32 + lg * 8]);
                ov[nt2] = __builtin_amdgcn_mfma_f32_16x16x32_bf16(ap, bv, ov[nt2], 0, 0, 0);
            }
        }
        // store O into XQ (row-private; only cols h*32.. touched this head)
        #pragma unroll
        for (int nt2 = 0; nt2 < 2; ++nt2)
            #pragma unroll
            for (int j = 0; j < 4; ++j)
                smem[LDS_XQ + (wid * 16 + lg * 4 + j) * 104 + h * 32 + nt2 * 16 + lr]
                    = f2s(ov[nt2][j]);
    }

    // ---------------- projection: [64x96] @ proj_w^T[96x96] ----------------
    f32x4 po[6];
    #pragma unroll
    for (int nt = 0; nt < 6; ++nt) po[nt] = (f32x4)0.f;
    #pragma unroll
    for (int ks = 0; ks < 3; ++ks) {
        bf16x8 a = *reinterpret_cast<const bf16x8*>(
            &smem[LDS_XQ + (wid * 16 + lr) * 104 + ks * 32 + lg * 8]);
        #pragma unroll
        for (int nt = 0; nt < 6; ++nt) {
            bf16x8 bp = ldw8(proj_w + (nt * 16 + lr) * 96 + ks * 32 + lg * 8);
            po[nt] = __builtin_amdgcn_mfma_f32_16x16x32_bf16(a, bp, po[nt], 0, 0, 0);
        }
    }
    #pragma unroll
    for (int nt = 0; nt < 6; ++nt) {
        int col = nt * 16 + lr;
        float pb = s2f(smem[LDS_PROJB + col]);
        #pragma unroll
        for (int j = 0; j < 4; ++j) {
            int n = wid * 16 + lg * 4 + j;
            if (n < 49)
                out[((size_t)w * 49 + n) * 96 + col] = po[nt][j] + pb;
        }
    }
}

// ---------------- prior highway: v_hw = proj(v(qkv(prior))) ----------------
__global__ __launch_bounds__(128)
void pawsa_prior(const float* __restrict__ uk, const float* __restrict__ fg,
                 const float* __restrict__ bg,
                 const float* __restrict__ qkv_w, const float* __restrict__ qkv_b,
                 const float* __restrict__ proj_w, const float* __restrict__ proj_b,
                 float* __restrict__ out_vhw)
{
    int blk = blockIdx.x;             // 24 = 8 batches * 3 priors
    int b = blk / 3, p = blk % 3;
    int t = threadIdx.x;
    __shared__ float prr[96], vf[96];
    const float* src = (p == 0) ? uk : (p == 1) ? fg : bg;
    if (t < 96) prr[t] = src[b * 96 + t];
    __syncthreads();
    if (t < 96) {
        float acc = qkv_b[192 + t];
        for (int k = 0; k < 96; ++k)
            acc += prr[k] * qkv_w[(192 + t) * 96 + k];
        vf[t] = acc;
    }
    __syncthreads();
    if (t < 96) {
        float acc = proj_b[t];
        for (int c = 0; c < 96; ++c)
            acc += vf[c] * proj_w[t * 96 + c];
        out_vhw[(b * 3 + p) * 96 + t] = acc;
    }
}

extern "C" void kernel_launch(void* const* d_in, const int* in_sizes, int n_in,
                              void* d_out, int out_size, void* d_ws, size_t ws_size,
                              hipStream_t stream) {
    const float* x          = (const float*)d_in[0];
    const float* mask       = (const float*)d_in[1];
    const float* uk         = (const float*)d_in[2];
    const float* fg         = (const float*)d_in[3];
    const float* bg         = (const float*)d_in[4];
    const float* qkv_w      = (const float*)d_in[5];
    const float* qkv_b      = (const float*)d_in[6];
    const float* proj_w     = (const float*)d_in[7];
    const float* proj_b     = (const float*)d_in[8];
    const float* bias_table = (const float*)d_in[9];
    float* out = (float*)d_out;

    pawsa_prior<<<24, 128, 0, stream>>>(uk, fg, bg, qkv_w, qkv_b, proj_w, proj_b,
                                        out + (size_t)8192 * 49 * 96);
    pawsa_main<<<8192, 256, 0, stream>>>(x, mask, uk, fg, bg, qkv_w, qkv_b,
                                         proj_w, proj_b, bias_table, out);
}

// Round 7
// 407.398 us; speedup vs baseline: 5.7753x; 1.0932x over previous
//
#include <hip/hip_runtime.h>
#include <hip/hip_bf16.h>

// ---------------------------------------------------------------------------
// PAWSA fused windowed attention, MI355X / gfx950 — round 7: register diet.
// Inputs f32, output f32 (out0 [8192,49,96], out1 v_hw [8,3,96] at elem
// offset 38,535,168). One block/window, 256 threads, bf16 MFMA 16x16x32.
// Key change vs r6: X held in 12 bf16x8 register fragments per lane (full
// 64x96 tile), QKV processed one N-tile at a time (acc[4] only) with
// immediate scatter -> peak regs ~115 (was ~180 incl. AGPR accs).
// LDS 42,792 B -> 3 blocks/CU;  occupancy target 12 waves/CU.
// Layout: XQ[52][104] | K[52][104] | P[52][68] | VT[96][68] | BIAS[516].
// X rows 52-63 = zero phantom overlapping K rows 0-11 (zero-staged).
// All phantom/overflow reads audited: land in finite regions; NaN-capable
// head-0 phantom K rows are column-isolated by MFMA and masked pre-exp.
// ---------------------------------------------------------------------------

typedef __bf16 bf16x8 __attribute__((ext_vector_type(8)));
typedef float  f32x4  __attribute__((ext_vector_type(4)));
typedef short  s16x4  __attribute__((ext_vector_type(4)));
using bf16 = __hip_bfloat16;

#define SCALE 0.17677669529663687f   // 32^-0.5

// LDS partition (units: 16-bit elements)
#define LDS_XQ    0       // [52][104] x_ext -> q (rows<52) -> O
#define LDS_K     5408    // [52][104] k  (rows 0-11 double as X zero phantom)
#define LDS_P     10816   // [52][68]  P (bf16 probs, per head)
#define LDS_VT    14352   // [96][68]  v transposed: vt[h*32+d][token]
#define LDS_BIAS  20880   // [516]     bias_table (bf16)
#define LDS_TOT   21396   // shorts -> 42,792 bytes

static __device__ inline float s2f(short s) {
    unsigned int u = ((unsigned int)(unsigned short)s) << 16;
    float f;
    __builtin_memcpy(&f, &u, 4);
    return f;
}
static __device__ inline short f2s(float f) {
    bf16 h = __float2bfloat16(f);
    short s;
    __builtin_memcpy(&s, &h, 2);
    return s;
}
// load 8 consecutive f32, convert to bf16x8 (MFMA operand fragment)
static __device__ inline bf16x8 ldw8(const float* p) {
    f32x4 a = *reinterpret_cast<const f32x4*>(p);
    f32x4 b = *reinterpret_cast<const f32x4*>(p + 4);
    bf16x8 r;
    #pragma unroll
    for (int i = 0; i < 4; ++i) {
        r[i]     = (__bf16)a[i];
        r[i + 4] = (__bf16)b[i];
    }
    return r;
}

__global__ __launch_bounds__(256, 3)
void pawsa_main(const float* __restrict__ x, const float* __restrict__ mask,
                const float* __restrict__ uk, const float* __restrict__ fg,
                const float* __restrict__ bg,
                const float* __restrict__ qkv_w, const float* __restrict__ qkv_b,
                const float* __restrict__ proj_w, const float* __restrict__ proj_b,
                const float* __restrict__ bias_table, float* __restrict__ out)
{
    __shared__ short smem[LDS_TOT];

    const int tid  = threadIdx.x;
    const int w    = blockIdx.x;       // window id
    const int b    = w >> 10;          // batch (nW = 1024)
    const int wi   = w & 1023;         // window-in-batch
    const int lane = tid & 63;
    const int wid  = tid >> 6;         // wave id 0..3
    const int lr   = lane & 15;        // row/col within 16-tile
    const int lg   = lane >> 4;        // k-group 0..3

    // ---- stage x_ext (f32->bf16) rows 0..51 into XQ; zero phantom rows ----
    #pragma unroll
    for (int it = 0; it < 6; ++it) {
        int idx = tid + it * 256;          // [64 rows][24 chunks of 4]
        int n = idx / 24, c4 = idx % 24;
        f32x4 v = (f32x4)0.f;
        if (n < 49) {
            v = *reinterpret_cast<const f32x4*>(x + ((size_t)w * 49 + n) * 96 + c4 * 4);
        } else if (n < 52) {
            const float* pr = (n == 49) ? uk : (n == 50) ? fg : bg;
            v = *reinterpret_cast<const f32x4*>(pr + b * 96 + c4 * 4);
        }
        s16x4 hv;
        #pragma unroll
        for (int i = 0; i < 4; ++i) hv[i] = f2s(v[i]);
        // rows 52..63 write zeros into K rows 0..11 (phantom X rows)
        *reinterpret_cast<s16x4*>(&smem[LDS_XQ + n * 104 + c4 * 4]) = hv;
    }
    for (int i = tid; i < 516; i += 256) smem[LDS_BIAS + i] = f2s(bias_table[i]);
    __syncthreads();

    // ---- load full X tile into registers: a[ks][mt], rows 52-63 = zeros ----
    bf16x8 af[3][4];
    #pragma unroll
    for (int ks = 0; ks < 3; ++ks)
        #pragma unroll
        for (int mt = 0; mt < 4; ++mt)
            af[ks][mt] = *reinterpret_cast<const bf16x8*>(
                &smem[LDS_XQ + (mt * 16 + lr) * 104 + ks * 32 + lg * 8]);
    __syncthreads();   // all waves done reading X before q overwrites XQ

    // ---- QKV GEMM, one N-tile at a time; immediate scatter ----
    // waves split 18 N-tiles {5,5,4,4}
    const int nt0   = wid * 5 - (wid == 3 ? 1 : 0);       // 0,5,10,14
    const int ntCnt = (wid < 2 ? 5 : 4);
    #pragma unroll
    for (int i = 0; i < 5; ++i) {
        if (i >= ntCnt) break;
        int nt = nt0 + i;
        f32x4 acc[4] = {(f32x4)0.f, (f32x4)0.f, (f32x4)0.f, (f32x4)0.f};
        #pragma unroll
        for (int ks = 0; ks < 3; ++ks) {
            bf16x8 bw = ldw8(qkv_w + (nt * 16 + lr) * 96 + ks * 32 + lg * 8);
            #pragma unroll
            for (int mt = 0; mt < 4; ++mt)
                acc[mt] = __builtin_amdgcn_mfma_f32_16x16x32_bf16(
                    af[ks][mt], bw, acc[mt], 0, 0, 0);
        }
        int o = nt * 16 + lr;                 // output channel 0..287
        float bias = qkv_b[o];                // L2-resident
        int s   = nt / 6;                     // 0=q 1=k 2=v
        int rem = o - s * 96;
        #pragma unroll
        for (int mt = 0; mt < 4; ++mt) {
            #pragma unroll
            for (int j = 0; j < 4; ++j) {
                int n = mt * 16 + lg * 4 + j;
                short hv = f2s(acc[mt][j] + bias);
                if (s == 0)      { if (n < 52) smem[LDS_XQ + n * 104 + rem] = hv; }
                else if (s == 1) { if (n < 52) smem[LDS_K  + n * 104 + rem] = hv; }
                else             smem[LDS_VT + rem * 68 + n] = hv;   // rows 52-63: finite bias
            }
        }
    }
    __syncthreads();
    // From here: K, VT read-only; XQ/P rows wave-private.

    // ---- hoist mask + relative-position bias index (head-independent) ----
    float mk[4][4];
    int   bidx[4][4];
    #pragma unroll
    for (int nt = 0; nt < 4; ++nt) {
        int c = nt * 16 + lr;                     // key col 0..63
        #pragma unroll
        for (int j = 0; j < 4; ++j) {
            int n = wid * 16 + lg * 4 + j;        // query row 0..63
            float m = 0.f;
            int idx = 171;
            if (c < 49) {
                idx = (n / 7 - c / 7 + 6) * 13 + ((n % 7) - (c % 7) + 6);
                if (idx > 171) idx = 171;         // garbage rows n>=49 (discarded)
                if (n < 49)
                    m = mask[(size_t)wi * 2401 + n * 49 + c];
            } else if (c < 52) {
                idx = 169 + (c - 49);
            }
            mk[nt][j] = m;
            bidx[nt][j] = idx;
        }
    }

    // ---- per-head attention (no barriers inside) ----
    #pragma unroll
    for (int h = 0; h < 3; ++h) {
        bf16x8 aq = *reinterpret_cast<const bf16x8*>(
            &smem[LDS_XQ + (wid * 16 + lr) * 104 + h * 32 + lg * 8]);
        f32x4 sacc[4];
        #pragma unroll
        for (int nt = 0; nt < 4; ++nt) {
            bf16x8 bk = *reinterpret_cast<const bf16x8*>(
                &smem[LDS_K + (nt * 16 + lr) * 104 + h * 32 + lg * 8]);
            sacc[nt] = __builtin_amdgcn_mfma_f32_16x16x32_bf16(aq, bk, (f32x4)0.f, 0, 0, 0);
        }
        float lgt[4][4];
        #pragma unroll
        for (int nt = 0; nt < 4; ++nt) {
            int c = nt * 16 + lr;
            #pragma unroll
            for (int j = 0; j < 4; ++j) {
                float v = -1e30f;
                if (c < 52)
                    v = sacc[nt][j] * SCALE
                        + s2f(smem[LDS_BIAS + bidx[nt][j] * 3 + h]) + mk[nt][j];
                lgt[nt][j] = v;
            }
        }
        float pr[4][4];
        #pragma unroll
        for (int j = 0; j < 4; ++j) {
            float m = fmaxf(fmaxf(lgt[0][j], lgt[1][j]), fmaxf(lgt[2][j], lgt[3][j]));
            m = fmaxf(m, __shfl_xor(m, 1));
            m = fmaxf(m, __shfl_xor(m, 2));
            m = fmaxf(m, __shfl_xor(m, 4));
            m = fmaxf(m, __shfl_xor(m, 8));
            float sum = 0.f;
            #pragma unroll
            for (int nt = 0; nt < 4; ++nt) {
                pr[nt][j] = __expf(lgt[nt][j] - m);
                sum += pr[nt][j];
            }
            sum += __shfl_xor(sum, 1);
            sum += __shfl_xor(sum, 2);
            sum += __shfl_xor(sum, 4);
            sum += __shfl_xor(sum, 8);
            float inv = 1.0f / sum;
            #pragma unroll
            for (int nt = 0; nt < 4; ++nt) pr[nt][j] *= inv;
        }
        #pragma unroll
        for (int nt = 0; nt < 4; ++nt)
            #pragma unroll
            for (int j = 0; j < 4; ++j) {
                int prow = wid * 16 + lg * 4 + j;
                if (prow < 52)
                    smem[LDS_P + prow * 68 + nt * 16 + lr] = f2s(pr[nt][j]);
            }

        // O_h = P @ V (K=52 padded to 64; P cols 52-63 exact zeros, VT finite)
        f32x4 ov[2] = {(f32x4)0.f, (f32x4)0.f};
        #pragma unroll
        for (int ks = 0; ks < 2; ++ks) {
            bf16x8 ap = *reinterpret_cast<const bf16x8*>(
                &smem[LDS_P + (wid * 16 + lr) * 68 + ks * 32 + lg * 8]);
            #pragma unroll
            for (int nt2 = 0; nt2 < 2; ++nt2) {
                bf16x8 bv = *reinterpret_cast<const bf16x8*>(
                    &smem[LDS_VT + (h * 32 + nt2 * 16 + lr) * 68 + ks * 32 + lg * 8]);
                ov[nt2] = __builtin_amdgcn_mfma_f32_16x16x32_bf16(ap, bv, ov[nt2], 0, 0, 0);
            }
        }
        #pragma unroll
        for (int nt2 = 0; nt2 < 2; ++nt2)
            #pragma unroll
            for (int j = 0; j < 4; ++j) {
                int orow = wid * 16 + lg * 4 + j;
                if (orow < 52)
                    smem[LDS_XQ + orow * 104 + h * 32 + nt2 * 16 + lr]
                        = f2s(ov[nt2][j]);
            }
    }

    // ---- projection: [64x96] @ proj_w^T[96x96] (wave-private rows) ----
    f32x4 po[6];
    #pragma unroll
    for (int nt = 0; nt < 6; ++nt) po[nt] = (f32x4)0.f;
    #pragma unroll
    for (int ks = 0; ks < 3; ++ks) {
        bf16x8 a = *reinterpret_cast<const bf16x8*>(
            &smem[LDS_XQ + (wid * 16 + lr) * 104 + ks * 32 + lg * 8]);
        #pragma unroll
        for (int nt = 0; nt < 6; ++nt) {
            bf16x8 bp = ldw8(proj_w + (nt * 16 + lr) * 96 + ks * 32 + lg * 8);
            po[nt] = __builtin_amdgcn_mfma_f32_16x16x32_bf16(a, bp, po[nt], 0, 0, 0);
        }
    }
    #pragma unroll
    for (int nt = 0; nt < 6; ++nt) {
        int col = nt * 16 + lr;
        float pb = proj_b[col];
        #pragma unroll
        for (int j = 0; j < 4; ++j) {
            int n = wid * 16 + lg * 4 + j;
            if (n < 49)
                out[((size_t)w * 49 + n) * 96 + col] = po[nt][j] + pb;
        }
    }
}

// ---------------- prior highway: v_hw = proj(v(qkv(prior))) ----------------
__global__ __launch_bounds__(128)
void pawsa_prior(const float* __restrict__ uk, const float* __restrict__ fg,
                 const float* __restrict__ bg,
                 const float* __restrict__ qkv_w, const float* __restrict__ qkv_b,
                 const float* __restrict__ proj_w, const float* __restrict__ proj_b,
                 float* __restrict__ out_vhw)
{
    int blk = blockIdx.x;             // 24 = 8 batches * 3 priors
    int b = blk / 3, p = blk % 3;
    int t = threadIdx.x;
    __shared__ float prr[96], vf[96];
    const float* src = (p == 0) ? uk : (p == 1) ? fg : bg;
    if (t < 96) prr[t] = src[b * 96 + t];
    __syncthreads();
    if (t < 96) {
        float acc = qkv_b[192 + t];
        for (int k = 0; k < 96; ++k)
            acc += prr[k] * qkv_w[(192 + t) * 96 + k];
        vf[t] = acc;
    }
    __syncthreads();
    if (t < 96) {
        float acc = proj_b[t];
        for (int c = 0; c < 96; ++c)
            acc += vf[c] * proj_w[t * 96 + c];
        out_vhw[(b * 3 + p) * 96 + t] = acc;
    }
}

extern "C" void kernel_launch(void* const* d_in, const int* in_sizes, int n_in,
                              void* d_out, int out_size, void* d_ws, size_t ws_size,
                              hipStream_t stream) {
    const float* x          = (const float*)d_in[0];
    const float* mask       = (const float*)d_in[1];
    const float* uk         = (const float*)d_in[2];
    const float* fg         = (const float*)d_in[3];
    const float* bg         = (const float*)d_in[4];
    const float* qkv_w      = (const float*)d_in[5];
    const float* qkv_b      = (const float*)d_in[6];
    const float* proj_w     = (const float*)d_in[7];
    const float* proj_b     = (const float*)d_in[8];
    const float* bias_table = (const float*)d_in[9];
    float* out = (float*)d_out;

    pawsa_prior<<<24, 128, 0, stream>>>(uk, fg, bg, qkv_w, qkv_b, proj_w, proj_b,
                                        out + (size_t)8192 * 49 * 96);
    pawsa_main<<<8192, 256, 0, stream>>>(x, mask, uk, fg, bg, qkv_w, qkv_b,
                                         proj_w, proj_b, bias_table, out);
}